// Round 1
// baseline (895.790 us; speedup 1.0000x reference)
//
#include <hip/hip_runtime.h>
#include <hip/hip_bf16.h>
#include <math.h>

#define NN 100000
#define NE 1000000
#define NG 2048
#define FIN 78
#define DD 32
#define TD 208
#define H1 170
#define H2 128
#define BN_EPS 1e-5f

// ---- static device workspace (module memory; fully rewritten every call) ----
__device__ float g_y[NN * DD];     // pre-aggregation node features (this layer)
__device__ float g_agg[NN * DD];   // y_i + sum_{j->i} y_j
__device__ float g_z[NN * DD];     // layer output before BN (raw)
__device__ float g_sum[DD];        // BN stat accumulators
__device__ float g_sq[DD];
__device__ float g_m[DD];          // BN mean / inv-std of last computed layer
__device__ float g_inv[DD];
__device__ float g_Wp[DD * DD];    // BN-folded next-layer weight: diag(inv) @ W
__device__ float g_c[DD];          // (m*inv) @ W  (subtract per node)
__device__ float g_pool[NG * DD];  // raw per-graph sums of z3
__device__ int   g_cnt[NG];        // per-graph node counts
__device__ float g_tm[TD];         // target BN mean
__device__ float g_ta[TD];         // target BN inv*gamma

__global__ void k_zero() {
    int i = blockIdx.x * blockDim.x + threadIdx.x;
    int stride = gridDim.x * blockDim.x;
    for (int j = i; j < NG * DD; j += stride) g_pool[j] = 0.f;
    for (int j = i; j < NG; j += stride) g_cnt[j] = 0;
    for (int j = i; j < DD; j += stride) { g_sum[j] = 0.f; g_sq[j] = 0.f; }
}

// y = x @ W11a (no bias; bias deferred post-aggregation). Also agg = y.
__global__ void k_lin1(const float* __restrict__ x, const float* __restrict__ W) {
    __shared__ float sW[FIN * DD];
    __shared__ float sx[8][FIN];
    for (int j = threadIdx.x; j < FIN * DD; j += blockDim.x) sW[j] = W[j];
    int nl = threadIdx.x >> 5, f = threadIdx.x & 31;
    const int nchunk = (NN + 7) / 8;
    for (int c = blockIdx.x; c < nchunk; c += gridDim.x) {
        int n0 = c * 8;
        __syncthreads();
        for (int j = threadIdx.x; j < 8 * FIN; j += blockDim.x) {
            int r = j / FIN, k = j - r * FIN;
            int n = n0 + r;
            sx[r][k] = (n < NN) ? x[n * FIN + k] : 0.f;
        }
        __syncthreads();
        int n = n0 + nl;
        if (n < NN) {
            float acc = 0.f;
            #pragma unroll
            for (int k = 0; k < FIN; ++k) acc += sx[nl][k] * sW[k * DD + f];
            g_y[n * DD + f] = acc;
            g_agg[n * DD + f] = acc;
        }
    }
}

// y = z @ Wp - c  (Wp = diag(inv)@W_next, c = (m*inv)@W_next). Also agg = y.
__global__ void k_lin_mid() {
    __shared__ float sW[DD * DD];
    __shared__ float sc[DD];
    __shared__ float sx[8][DD];
    for (int j = threadIdx.x; j < DD * DD; j += blockDim.x) sW[j] = g_Wp[j];
    if (threadIdx.x < DD) sc[threadIdx.x] = g_c[threadIdx.x];
    int nl = threadIdx.x >> 5, f = threadIdx.x & 31;
    const int nchunk = (NN + 7) / 8;
    for (int c = blockIdx.x; c < nchunk; c += gridDim.x) {
        int n0 = c * 8;
        __syncthreads();
        for (int j = threadIdx.x; j < 8 * DD; j += blockDim.x) {
            int r = j >> 5, k = j & 31;
            int n = n0 + r;
            sx[r][k] = (n < NN) ? g_z[n * DD + k] : 0.f;
        }
        __syncthreads();
        int n = n0 + nl;
        if (n < NN) {
            float acc = -sc[f];
            #pragma unroll
            for (int k = 0; k < DD; ++k) acc += sx[nl][k] * sW[k * DD + f];
            g_y[n * DD + f] = acc;
            g_agg[n * DD + f] = acc;
        }
    }
}

// agg[dst] += y[src] over all edges (32 lanes per edge).
__global__ void k_edge(const int* __restrict__ ei) {
    int idx = blockIdx.x * blockDim.x + threadIdx.x;
    int e = idx >> 5;
    int f = idx & 31;
    int s = ei[e], d = ei[NE + e];
    atomicAdd(&g_agg[d * DD + f], g_y[s * DD + f]);
}

// z = act(relu(agg + ba) @ Wb + bb); accumulate BN stats. ACT 0=elu, 1=relu.
template <int ACT>
__global__ void k_post(const float* __restrict__ ba, const float* __restrict__ Wb,
                       const float* __restrict__ bb) {
    __shared__ float sW[DD * DD];
    __shared__ float sb[DD];
    __shared__ float sbb[DD];
    __shared__ float srow[8][DD];
    __shared__ float sred[256];
    for (int j = threadIdx.x; j < DD * DD; j += blockDim.x) sW[j] = Wb[j];
    if (threadIdx.x < DD) { sb[threadIdx.x] = ba[threadIdx.x]; sbb[threadIdx.x] = bb[threadIdx.x]; }
    int nl = threadIdx.x >> 5, f = threadIdx.x & 31;
    float ls = 0.f, lq = 0.f;
    const int nchunk = (NN + 7) / 8;
    for (int c = blockIdx.x; c < nchunk; c += gridDim.x) {
        int n0 = c * 8;
        __syncthreads();
        int n = n0 + nl;
        float v = (n < NN) ? g_agg[n * DD + f] + sb[f] : 0.f;
        srow[nl][f] = fmaxf(v, 0.f);
        __syncthreads();
        if (n < NN) {
            float acc = sbb[f];
            #pragma unroll
            for (int k = 0; k < DD; ++k) acc += srow[nl][k] * sW[k * DD + f];
            float zv;
            if (ACT == 0) zv = (acc > 0.f) ? acc : (__expf(acc) - 1.f);
            else          zv = fmaxf(acc, 0.f);
            g_z[n * DD + f] = zv;
            ls += zv; lq += zv * zv;
        }
    }
    __syncthreads();
    sred[threadIdx.x] = ls;
    __syncthreads();
    for (int s = 128; s >= 32; s >>= 1) {
        if (threadIdx.x < s) sred[threadIdx.x] += sred[threadIdx.x + s];
        __syncthreads();
    }
    if (threadIdx.x < 32) atomicAdd(&g_sum[f], sred[threadIdx.x]);
    __syncthreads();
    sred[threadIdx.x] = lq;
    __syncthreads();
    for (int s = 128; s >= 32; s >>= 1) {
        if (threadIdx.x < s) sred[threadIdx.x] += sred[threadIdx.x + s];
        __syncthreads();
    }
    if (threadIdx.x < 32) atomicAdd(&g_sq[f], sred[threadIdx.x]);
}

// Finalize BN stats; if NEXT, fold into next layer's weight (Wp, c). Re-zero accumulators.
template <bool NEXT>
__global__ void k_fold(const float* __restrict__ Wn) {
    __shared__ float sm[DD], sinv[DD], sWp[DD * DD];
    int t = threadIdx.x;
    if (t < DD) {
        float m = g_sum[t] * (1.f / NN);
        float v = g_sq[t] * (1.f / NN) - m * m;
        float iv = rsqrtf(v + BN_EPS);
        sm[t] = m; sinv[t] = iv;
        g_m[t] = m; g_inv[t] = iv;
        g_sum[t] = 0.f; g_sq[t] = 0.f;
    }
    __syncthreads();
    if (NEXT) {
        for (int j = t; j < DD * DD; j += blockDim.x) {
            int k = j >> 5;
            float w = sinv[k] * Wn[j];
            sWp[j] = w;
            g_Wp[j] = w;
        }
        __syncthreads();
        if (t < DD) {
            float c = 0.f;
            #pragma unroll
            for (int k = 0; k < DD; ++k) c += sm[k] * sWp[k * DD + t];
            g_c[t] = c;
        }
    }
}

__global__ void k_pool(const int* __restrict__ batch) {
    int idx = blockIdx.x * blockDim.x + threadIdx.x;
    int n = idx >> 5;
    if (n >= NN) return;
    int f = idx & 31;
    int b = batch[n];
    atomicAdd(&g_pool[b * DD + f], g_z[n * DD + f]);
    if (f == 0) atomicAdd(&g_cnt[b], 1);
}

// g_out = relu( (inv3*(pool - cnt*m3)) @ Wn2 + bn2b )   -> written to d_out+NG
__global__ void k_head_g(const float* __restrict__ Wn2, const float* __restrict__ bn2b,
                         float* __restrict__ out_g) {
    __shared__ float sh[DD];
    int b = blockIdx.x, t = threadIdx.x;
    if (t < DD) {
        float cf = (float)g_cnt[b];
        sh[t] = g_inv[t] * (g_pool[b * DD + t] - cf * g_m[t]);
    }
    __syncthreads();
    float acc = bn2b[t];
    #pragma unroll
    for (int k = 0; k < DD; ++k) acc += sh[k] * Wn2[k * H2 + t];
    out_g[b * H2 + t] = fmaxf(acc, 0.f);
}

__global__ void k_tstats(const float* __restrict__ target, const float* __restrict__ g1) {
    __shared__ float ssum[256], ssq[256];
    int f = blockIdx.x, t = threadIdx.x;
    float ls = 0.f, lq = 0.f;
    for (int b = t; b < NG; b += 256) { float v = target[b * TD + f]; ls += v; lq += v * v; }
    ssum[t] = ls; ssq[t] = lq;
    __syncthreads();
    for (int s = 128; s >= 1; s >>= 1) {
        if (t < s) { ssum[t] += ssum[t + s]; ssq[t] += ssq[t + s]; }
        __syncthreads();
    }
    if (t == 0) {
        float m = ssum[0] * (1.f / NG);
        float v = ssq[0] * (1.f / NG) - m * m;
        g_tm[f] = m;
        g_ta[f] = rsqrtf(v + BN_EPS) * g1[f];
    }
}

// Per-graph fused head: BN(target)->W31->W32->softmax, concat with g, W4->relu, W5->sigmoid.
__global__ void k_head_t(const float* __restrict__ target, const float* __restrict__ be1,
                         const float* __restrict__ W31, const float* __restrict__ b31,
                         const float* __restrict__ W32, const float* __restrict__ b32,
                         const float* __restrict__ W4, const float* __restrict__ b4,
                         const float* __restrict__ W5, const float* __restrict__ b5,
                         const float* __restrict__ gmat, float* __restrict__ out) {
    __shared__ float tbn[TD];
    __shared__ float t1[H1];
    __shared__ float smx[H2];
    __shared__ float gl[H2];
    __shared__ float red[128];
    __shared__ float xr[H2];
    int b = blockIdx.x, t = threadIdx.x;
    for (int j = t; j < TD; j += 256)
        tbn[j] = (target[b * TD + j] - g_tm[j]) * g_ta[j] + be1[j];
    if (t < H2) gl[t] = gmat[b * H2 + t];
    __syncthreads();
    if (t < H1) {
        float acc = b31[t];
        for (int f = 0; f < TD; ++f) acc += tbn[f] * W31[f * H1 + t];
        t1[t] = acc;
    }
    __syncthreads();
    float tv = 0.f;
    if (t < H2) {
        float acc = b32[t];
        for (int j = 0; j < H1; ++j) acc += t1[j] * W32[j * H2 + t];
        tv = acc;
    }
    if (t < H2) red[t] = tv;
    __syncthreads();
    for (int s = 64; s >= 1; s >>= 1) { if (t < s) red[t] = fmaxf(red[t], red[t + s]); __syncthreads(); }
    float mx = red[0];
    __syncthreads();
    float ex = 0.f;
    if (t < H2) { ex = __expf(tv - mx); red[t] = ex; }
    __syncthreads();
    for (int s = 64; s >= 1; s >>= 1) { if (t < s) red[t] += red[t + s]; __syncthreads(); }
    float isum = 1.f / red[0];
    __syncthreads();
    if (t < H2) smx[t] = ex * isum;
    __syncthreads();
    if (t < H2) {
        float acc = b4[t];
        #pragma unroll 4
        for (int i = 0; i < H2; ++i)
            acc += gl[i] * W4[i * H2 + t] + smx[i] * W4[(H2 + i) * H2 + t];
        xr[t] = fmaxf(acc, 0.f);
    }
    __syncthreads();
    if (t < H2) red[t] = xr[t] * W5[t]; else if (t < 256) {}
    __syncthreads();
    for (int s = 64; s >= 1; s >>= 1) { if (t < s) red[t] += red[t + s]; __syncthreads(); }
    if (t == 0) out[b] = 1.f / (1.f + __expf(-(red[0] + b5[0])));
}

extern "C" void kernel_launch(void* const* d_in, const int* in_sizes, int n_in,
                              void* d_out, int out_size, void* d_ws, size_t ws_size,
                              hipStream_t stream) {
    const float* x      = (const float*)d_in[0];
    const int*   ei     = (const int*)d_in[1];
    const int*   batch  = (const int*)d_in[2];
    const float* target = (const float*)d_in[3];
    const float* W11a = (const float*)d_in[4];
    const float* b11a = (const float*)d_in[5];
    const float* W11b = (const float*)d_in[6];
    const float* b11b = (const float*)d_in[7];
    const float* W12a = (const float*)d_in[8];
    const float* b12a = (const float*)d_in[9];
    const float* W12b = (const float*)d_in[10];
    const float* b12b = (const float*)d_in[11];
    const float* W13a = (const float*)d_in[12];
    const float* b13a = (const float*)d_in[13];
    const float* W13b = (const float*)d_in[14];
    const float* b13b = (const float*)d_in[15];
    const float* Wn2  = (const float*)d_in[16];
    const float* bn2b = (const float*)d_in[17];
    const float* g1   = (const float*)d_in[18];
    const float* be1  = (const float*)d_in[19];
    const float* W31  = (const float*)d_in[20];
    const float* b31  = (const float*)d_in[21];
    const float* W32  = (const float*)d_in[22];
    const float* b32  = (const float*)d_in[23];
    const float* W4   = (const float*)d_in[24];
    const float* b4   = (const float*)d_in[25];
    const float* W5   = (const float*)d_in[26];
    const float* b5   = (const float*)d_in[27];
    float* out   = (float*)d_out;
    float* out_g = out + NG;

    k_zero<<<256, 256, 0, stream>>>();

    // --- layer 1 ---
    k_lin1<<<2048, 256, 0, stream>>>(x, W11a);
    k_edge<<<(NE * 32) / 256, 256, 0, stream>>>(ei);
    k_post<0><<<1024, 256, 0, stream>>>(b11a, W11b, b11b);
    k_fold<true><<<1, 256, 0, stream>>>(W12a);

    // --- layer 2 ---
    k_lin_mid<<<2048, 256, 0, stream>>>();
    k_edge<<<(NE * 32) / 256, 256, 0, stream>>>(ei);
    k_post<1><<<1024, 256, 0, stream>>>(b12a, W12b, b12b);
    k_fold<true><<<1, 256, 0, stream>>>(W13a);

    // --- layer 3 ---
    k_lin_mid<<<2048, 256, 0, stream>>>();
    k_edge<<<(NE * 32) / 256, 256, 0, stream>>>(ei);
    k_post<1><<<1024, 256, 0, stream>>>(b13a, W13b, b13b);
    k_fold<false><<<1, 256, 0, stream>>>(nullptr);

    // --- pooling + head ---
    k_pool<<<(NN * 32 + 255) / 256, 256, 0, stream>>>(batch);
    k_head_g<<<NG, 128, 0, stream>>>(Wn2, bn2b, out_g);
    k_tstats<<<TD, 256, 0, stream>>>(target, g1);
    k_head_t<<<NG, 256, 0, stream>>>(target, be1, W31, b31, W32, b32, W4, b4, W5, b5,
                                     out_g, out);
}

// Round 3
// 658.270 us; speedup vs baseline: 1.3608x; 1.3608x over previous
//
#include <hip/hip_runtime.h>
#include <hip/hip_bf16.h>
#include <math.h>

#define NN 100000
#define NE 1000000
#define NG 2048
#define FIN 78
#define DD 32
#define TD 208
#define H1 170
#define H2 128
#define BN_EPS 1e-5f
#define SCAN_BLK 1024
#define NB_SCAN ((NN + SCAN_BLK - 1) / SCAN_BLK)   // 98

// ---- static device workspace (module memory; fully rewritten every call) ----
__device__ float g_y[NN * DD];      // layer-1 pre-aggregation features (x @ W11a)
__device__ float g_za[NN * DD];     // z ping buffer (layer1 out, layer3 out)
__device__ float g_zb[NN * DD];     // z pong buffer (layer2 out)
__device__ float g_sum[DD];         // BN stat accumulators
__device__ float g_sq[DD];
__device__ float g_m[DD];           // BN mean / inv-std of last computed layer
__device__ float g_inv[DD];
__device__ float g_Wp[DD * DD];     // BN-folded next-layer weight: diag(inv) @ W
__device__ float g_c[DD];           // (m*inv) @ W  (subtract per node per (deg+1))
__device__ float g_tm[TD];          // target BN mean
__device__ float g_ta[TD];          // target BN inv*gamma
// CSR-by-dst build
__device__ int g_deg[NN];
__device__ int g_tmp[NN];           // per-block inclusive scans
__device__ int g_bsum[NB_SCAN];
__device__ int g_bpre[NB_SCAN];
__device__ int g_rowptr[NN + 1];
__device__ int g_cur[NN + 1];
__device__ int g_srcs[NE];

__global__ void k_zero() {
    int i = blockIdx.x * blockDim.x + threadIdx.x;
    int stride = gridDim.x * blockDim.x;
    for (int j = i; j < NN; j += stride) g_deg[j] = 0;
    if (i < DD) { g_sum[i] = 0.f; g_sq[i] = 0.f; }
}

// ---------------- CSR build (by destination) ----------------
__global__ void k_hist(const int* __restrict__ ei) {
    int e = blockIdx.x * blockDim.x + threadIdx.x;
    if (e < NE) atomicAdd(&g_deg[ei[NE + e]], 1);
}

__global__ void k_scan1() {
    __shared__ int s[SCAN_BLK];
    int b = blockIdx.x, t = threadIdx.x;
    int i = b * SCAN_BLK + t;
    int v = (i < NN) ? g_deg[i] : 0;
    s[t] = v;
    __syncthreads();
    for (int o = 1; o < SCAN_BLK; o <<= 1) {
        int u = (t >= o) ? s[t - o] : 0;
        __syncthreads();
        s[t] += u;
        __syncthreads();
    }
    if (i < NN) g_tmp[i] = s[t];
    if (t == SCAN_BLK - 1) g_bsum[b] = s[t];
}

__global__ void k_scan2() {
    __shared__ int s[128];
    int t = threadIdx.x;
    int v = (t < NB_SCAN) ? g_bsum[t] : 0;
    s[t] = v;
    __syncthreads();
    for (int o = 1; o < 128; o <<= 1) {
        int u = (t >= o) ? s[t - o] : 0;
        __syncthreads();
        s[t] += u;
        __syncthreads();
    }
    if (t < NB_SCAN) g_bpre[t] = s[t] - v;   // exclusive
}

__global__ void k_scan3() {
    int i = blockIdx.x * blockDim.x + threadIdx.x;
    if (i >= NN) return;
    int R = g_tmp[i] + g_bpre[i >> 10];
    g_rowptr[i + 1] = R;
    g_cur[i + 1] = R;
    if (i == 0) { g_rowptr[0] = 0; g_cur[0] = 0; }
}

__global__ void k_scatter(const int* __restrict__ ei) {
    int e = blockIdx.x * blockDim.x + threadIdx.x;
    if (e >= NE) return;
    int s = ei[e], d = ei[NE + e];
    int pos = atomicAdd(&g_cur[d], 1);
    g_srcs[pos] = s;
}

// ---------------- layer 1 node linear: y = x @ W11a ----------------
__global__ void k_lin1(const float* __restrict__ x, const float* __restrict__ W) {
    __shared__ float sW[FIN * DD];
    __shared__ float sx[8][FIN];
    for (int j = threadIdx.x; j < FIN * DD; j += blockDim.x) sW[j] = W[j];
    int nl = threadIdx.x >> 5, f = threadIdx.x & 31;
    const int nchunk = (NN + 7) / 8;
    for (int c = blockIdx.x; c < nchunk; c += gridDim.x) {
        int n0 = c * 8;
        __syncthreads();
        for (int j = threadIdx.x; j < 8 * FIN; j += blockDim.x) {
            int r = j / FIN, k = j - r * FIN;
            int n = n0 + r;
            sx[r][k] = (n < NN) ? x[n * FIN + k] : 0.f;
        }
        __syncthreads();
        int n = n0 + nl;
        if (n < NN) {
            float acc = 0.f;
            #pragma unroll
            for (int k = 0; k < FIN; ++k) acc += sx[nl][k] * sW[k * DD + f];
            g_y[n * DD + f] = acc;
        }
    }
}

// block-level BN stat reduction helper body (expects sred[256])
#define BN_REDUCE(ls, lq)                                                      \
    do {                                                                       \
        __syncthreads();                                                       \
        sred[threadIdx.x] = (ls);                                              \
        __syncthreads();                                                       \
        for (int s_ = 128; s_ >= 32; s_ >>= 1) {                               \
            if (threadIdx.x < s_) sred[threadIdx.x] += sred[threadIdx.x + s_]; \
            __syncthreads();                                                   \
        }                                                                      \
        if (threadIdx.x < 32) atomicAdd(&g_sum[threadIdx.x], sred[threadIdx.x]);\
        __syncthreads();                                                       \
        sred[threadIdx.x] = (lq);                                              \
        __syncthreads();                                                       \
        for (int s_ = 128; s_ >= 32; s_ >>= 1) {                               \
            if (threadIdx.x < s_) sred[threadIdx.x] += sred[threadIdx.x + s_]; \
            __syncthreads();                                                   \
        }                                                                      \
        if (threadIdx.x < 32) atomicAdd(&g_sq[threadIdx.x], sred[threadIdx.x]);\
    } while (0)

// layer 1: gather y (agg = y_i + sum y_src), z1 = elu(relu(agg+ba) @ Wb + bb) -> g_za
__global__ void k_gp1(const float* __restrict__ ba, const float* __restrict__ Wb,
                      const float* __restrict__ bb) {
    __shared__ float sW[DD * DD];
    __shared__ float sba[DD], sbb[DD];
    __shared__ float srow[8][DD];
    __shared__ float sred[256];
    for (int j = threadIdx.x; j < DD * DD; j += blockDim.x) sW[j] = Wb[j];
    if (threadIdx.x < DD) { sba[threadIdx.x] = ba[threadIdx.x]; sbb[threadIdx.x] = bb[threadIdx.x]; }
    __syncthreads();
    int g = threadIdx.x >> 5, f = threadIdx.x & 31;
    float ls = 0.f, lq = 0.f;
    const int nchunk = (NN + 7) / 8;
    for (int c = blockIdx.x; c < nchunk; c += gridDim.x) {
        int n = c * 8 + g;
        float u = 0.f;
        if (n < NN) {
            float acc = g_y[n * DD + f];
            int p = g_rowptr[n], e = g_rowptr[n + 1];
            for (; p + 4 <= e; p += 4) {
                int s0 = g_srcs[p], s1 = g_srcs[p + 1], s2 = g_srcs[p + 2], s3 = g_srcs[p + 3];
                acc += g_y[s0 * DD + f] + g_y[s1 * DD + f] + g_y[s2 * DD + f] + g_y[s3 * DD + f];
            }
            for (; p < e; ++p) acc += g_y[g_srcs[p] * DD + f];
            u = fmaxf(acc + sba[f], 0.f);
        }
        srow[g][f] = u;   // row private to this 32-lane group: no barrier needed
        float accz = sbb[f];
        #pragma unroll
        for (int k = 0; k < DD; ++k) accz += srow[g][k] * sW[k * DD + f];
        if (n < NN) {
            float zv = (accz > 0.f) ? accz : (__expf(accz) - 1.f);
            g_za[n * DD + f] = zv;
            ls += zv; lq += zv * zv;
        }
    }
    BN_REDUCE(ls, lq);
}

// layers 2/3: gather raw z, apply BN-folded linear via linearity:
//   agg_z = z_i + sum z_src;  v = agg_z @ Wp - (deg+1)*c + ba;  u = relu(v)
//   z' = relu(u @ Wb + bb)
// DIR=0: read g_za write g_zb.  DIR=1: read g_zb write g_za.
template <int DIR>
__global__ void k_gp2(const float* __restrict__ ba, const float* __restrict__ Wb,
                      const float* __restrict__ bb) {
    __shared__ float sWp[DD * DD];
    __shared__ float sW[DD * DD];
    __shared__ float sc[DD], sba[DD], sbb[DD];
    __shared__ float srow[8][DD];
    __shared__ float srow2[8][DD];
    __shared__ float sred[256];
    for (int j = threadIdx.x; j < DD * DD; j += blockDim.x) { sWp[j] = g_Wp[j]; sW[j] = Wb[j]; }
    if (threadIdx.x < DD) {
        sc[threadIdx.x] = g_c[threadIdx.x];
        sba[threadIdx.x] = ba[threadIdx.x];
        sbb[threadIdx.x] = bb[threadIdx.x];
    }
    __syncthreads();
    const float* zin = (DIR == 0) ? g_za : g_zb;
    float* zout      = (DIR == 0) ? g_zb : g_za;
    int g = threadIdx.x >> 5, f = threadIdx.x & 31;
    float ls = 0.f, lq = 0.f;
    const int nchunk = (NN + 7) / 8;
    for (int c = blockIdx.x; c < nchunk; c += gridDim.x) {
        int n = c * 8 + g;
        float aggz = 0.f; int deg = 0;
        if (n < NN) {
            aggz = zin[n * DD + f];
            int p = g_rowptr[n], e = g_rowptr[n + 1];
            deg = e - p;
            for (; p + 4 <= e; p += 4) {
                int s0 = g_srcs[p], s1 = g_srcs[p + 1], s2 = g_srcs[p + 2], s3 = g_srcs[p + 3];
                aggz += zin[s0 * DD + f] + zin[s1 * DD + f] + zin[s2 * DD + f] + zin[s3 * DD + f];
            }
            for (; p < e; ++p) aggz += zin[g_srcs[p] * DD + f];
        }
        srow[g][f] = aggz;   // half-wave private row
        float v = sba[f] - (float)(deg + 1) * sc[f];
        #pragma unroll
        for (int k = 0; k < DD; ++k) v += srow[g][k] * sWp[k * DD + f];
        srow2[g][f] = fmaxf(v, 0.f);
        float accz = sbb[f];
        #pragma unroll
        for (int k = 0; k < DD; ++k) accz += srow2[g][k] * sW[k * DD + f];
        if (n < NN) {
            float zv = fmaxf(accz, 0.f);
            zout[n * DD + f] = zv;
            ls += zv; lq += zv * zv;
        }
    }
    BN_REDUCE(ls, lq);
}

// Finalize BN stats; if NEXT, fold into next layer's weight (Wp, c). Re-zero accumulators.
template <bool NEXT>
__global__ void k_fold(const float* __restrict__ Wn) {
    __shared__ float sm[DD], sinv[DD], sWp[DD * DD];
    int t = threadIdx.x;
    if (t < DD) {
        float m = g_sum[t] * (1.f / NN);
        float v = g_sq[t] * (1.f / NN) - m * m;
        float iv = rsqrtf(v + BN_EPS);
        sm[t] = m; sinv[t] = iv;
        g_m[t] = m; g_inv[t] = iv;
        g_sum[t] = 0.f; g_sq[t] = 0.f;
    }
    __syncthreads();
    if (NEXT) {
        for (int j = t; j < DD * DD; j += blockDim.x) {
            int k = j >> 5;
            float w = sinv[k] * Wn[j];
            sWp[j] = w;
            g_Wp[j] = w;
        }
        __syncthreads();
        if (t < DD) {
            float c = 0.f;
            #pragma unroll
            for (int k = 0; k < DD; ++k) c += sm[k] * sWp[k * DD + t];
            g_c[t] = c;
        }
    }
}

// pooling (sorted batch -> per-graph contiguous range) fused with BN fold + Wn2 head
__global__ void k_pool_head_g(const int* __restrict__ batch, const float* __restrict__ Wn2,
                              const float* __restrict__ bn2b, float* __restrict__ out_g) {
    __shared__ float sh[DD];
    __shared__ float sp[4][DD];
    __shared__ int bnd[2];
    int b = blockIdx.x, t = threadIdx.x;   // 128 threads
    if (t < 2) {
        int key = b + t;                   // lower_bound(batch, key)
        int lo = 0, hi = NN;
        while (lo < hi) { int mid = (lo + hi) >> 1; if (batch[mid] < key) lo = mid + 1; else hi = mid; }
        bnd[t] = lo;
    }
    __syncthreads();
    int s0 = bnd[0], s1 = bnd[1];
    int r = t >> 5, f = t & 31;
    float acc = 0.f;
    for (int n = s0 + r; n < s1; n += 4) acc += g_za[n * DD + f];
    sp[r][f] = acc;
    __syncthreads();
    if (t < DD) {
        float tot = sp[0][t] + sp[1][t] + sp[2][t] + sp[3][t];
        float cf = (float)(s1 - s0);
        sh[t] = g_inv[t] * (tot - cf * g_m[t]);
    }
    __syncthreads();
    float a2 = bn2b[t];
    #pragma unroll
    for (int k = 0; k < DD; ++k) a2 += sh[k] * Wn2[k * H2 + t];
    out_g[b * H2 + t] = fmaxf(a2, 0.f);
}

__global__ void k_tstats(const float* __restrict__ target, const float* __restrict__ g1) {
    __shared__ float ssum[256], ssq[256];
    int f = blockIdx.x, t = threadIdx.x;
    float ls = 0.f, lq = 0.f;
    for (int b = t; b < NG; b += 256) { float v = target[b * TD + f]; ls += v; lq += v * v; }
    ssum[t] = ls; ssq[t] = lq;
    __syncthreads();
    for (int s = 128; s >= 1; s >>= 1) {
        if (t < s) { ssum[t] += ssum[t + s]; ssq[t] += ssq[t + s]; }
        __syncthreads();
    }
    if (t == 0) {
        float m = ssum[0] * (1.f / NG);
        float v = ssq[0] * (1.f / NG) - m * m;
        g_tm[f] = m;
        g_ta[f] = rsqrtf(v + BN_EPS) * g1[f];
    }
}

// Per-graph fused head: BN(target)->W31->W32->softmax, concat with g, W4->relu, W5->sigmoid.
__global__ void k_head_t(const float* __restrict__ target, const float* __restrict__ be1,
                         const float* __restrict__ W31, const float* __restrict__ b31,
                         const float* __restrict__ W32, const float* __restrict__ b32,
                         const float* __restrict__ W4, const float* __restrict__ b4,
                         const float* __restrict__ W5, const float* __restrict__ b5,
                         const float* __restrict__ gmat, float* __restrict__ out) {
    __shared__ float tbn[TD];
    __shared__ float t1[H1];
    __shared__ float smx[H2];
    __shared__ float gl[H2];
    __shared__ float red[128];
    __shared__ float xr[H2];
    int b = blockIdx.x, t = threadIdx.x;
    for (int j = t; j < TD; j += 256)
        tbn[j] = (target[b * TD + j] - g_tm[j]) * g_ta[j] + be1[j];
    if (t < H2) gl[t] = gmat[b * H2 + t];
    __syncthreads();
    if (t < H1) {
        float acc = b31[t];
        for (int f = 0; f < TD; ++f) acc += tbn[f] * W31[f * H1 + t];
        t1[t] = acc;
    }
    __syncthreads();
    float tv = 0.f;
    if (t < H2) {
        float acc = b32[t];
        for (int j = 0; j < H1; ++j) acc += t1[j] * W32[j * H2 + t];
        tv = acc;
    }
    if (t < H2) red[t] = tv;
    __syncthreads();
    for (int s = 64; s >= 1; s >>= 1) { if (t < s) red[t] = fmaxf(red[t], red[t + s]); __syncthreads(); }
    float mx = red[0];
    __syncthreads();
    float ex = 0.f;
    if (t < H2) { ex = __expf(tv - mx); red[t] = ex; }
    __syncthreads();
    for (int s = 64; s >= 1; s >>= 1) { if (t < s) red[t] += red[t + s]; __syncthreads(); }
    float isum = 1.f / red[0];
    __syncthreads();
    if (t < H2) smx[t] = ex * isum;
    __syncthreads();
    if (t < H2) {
        float acc = b4[t];
        #pragma unroll 4
        for (int i = 0; i < H2; ++i)
            acc += gl[i] * W4[i * H2 + t] + smx[i] * W4[(H2 + i) * H2 + t];
        xr[t] = fmaxf(acc, 0.f);
    }
    __syncthreads();
    if (t < H2) red[t] = xr[t] * W5[t];
    __syncthreads();
    for (int s = 64; s >= 1; s >>= 1) { if (t < s) red[t] += red[t + s]; __syncthreads(); }
    if (t == 0) out[b] = 1.f / (1.f + __expf(-(red[0] + b5[0])));
}

extern "C" void kernel_launch(void* const* d_in, const int* in_sizes, int n_in,
                              void* d_out, int out_size, void* d_ws, size_t ws_size,
                              hipStream_t stream) {
    const float* x      = (const float*)d_in[0];
    const int*   ei     = (const int*)d_in[1];
    const int*   batch  = (const int*)d_in[2];
    const float* target = (const float*)d_in[3];
    const float* W11a = (const float*)d_in[4];
    const float* b11a = (const float*)d_in[5];
    const float* W11b = (const float*)d_in[6];
    const float* b11b = (const float*)d_in[7];
    const float* W12a = (const float*)d_in[8];
    const float* b12a = (const float*)d_in[9];
    const float* W12b = (const float*)d_in[10];
    const float* b12b = (const float*)d_in[11];
    const float* W13a = (const float*)d_in[12];
    const float* b13a = (const float*)d_in[13];
    const float* W13b = (const float*)d_in[14];
    const float* b13b = (const float*)d_in[15];
    const float* Wn2  = (const float*)d_in[16];
    const float* bn2b = (const float*)d_in[17];
    const float* g1   = (const float*)d_in[18];
    const float* be1  = (const float*)d_in[19];
    const float* W31  = (const float*)d_in[20];
    const float* b31  = (const float*)d_in[21];
    const float* W32  = (const float*)d_in[22];
    const float* b32  = (const float*)d_in[23];
    const float* W4   = (const float*)d_in[24];
    const float* b4   = (const float*)d_in[25];
    const float* W5   = (const float*)d_in[26];
    const float* b5   = (const float*)d_in[27];
    float* out   = (float*)d_out;
    float* out_g = out + NG;

    // --- CSR build (by dst) ---
    k_zero<<<256, 256, 0, stream>>>();
    k_hist<<<(NE + 255) / 256, 256, 0, stream>>>(ei);
    k_scan1<<<NB_SCAN, SCAN_BLK, 0, stream>>>();
    k_scan2<<<1, 128, 0, stream>>>();
    k_scan3<<<(NN + 255) / 256, 256, 0, stream>>>();
    k_scatter<<<(NE + 255) / 256, 256, 0, stream>>>(ei);

    // --- layer 1 ---
    k_lin1<<<2048, 256, 0, stream>>>(x, W11a);
    k_gp1<<<2560, 256, 0, stream>>>(b11a, W11b, b11b);
    k_fold<true><<<1, 256, 0, stream>>>(W12a);

    // --- layer 2 (za -> zb) ---
    k_gp2<0><<<2560, 256, 0, stream>>>(b12a, W12b, b12b);
    k_fold<true><<<1, 256, 0, stream>>>(W13a);

    // --- layer 3 (zb -> za) ---
    k_gp2<1><<<2560, 256, 0, stream>>>(b13a, W13b, b13b);
    k_fold<false><<<1, 256, 0, stream>>>(nullptr);

    // --- pooling + head ---
    k_pool_head_g<<<NG, 128, 0, stream>>>(batch, Wn2, bn2b, out_g);
    k_tstats<<<TD, 256, 0, stream>>>(target, g1);
    k_head_t<<<NG, 256, 0, stream>>>(target, be1, W31, b31, W32, b32, W4, b4, W5, b5,
                                     out_g, out);
}